// Round 17
// baseline (193.902 us; speedup 1.0000x reference)
//
#include <hip/hip_runtime.h>

// Fused: z = x @ W^T + b_lin; y = swish(z) + b_ex; GroupNorm(32 groups) * gn_w + gn_b
// x: [8192, 2048] f32, W: [4096, 2048] f32, out: [8192, 4096] f32
// Round 17 (FINAL CONFIG): R15 verbatim = best verified GEMM (172-174us,
// MfmaUtil 37%, occ 40%, 0 conflicts) + single fused f32->bf16 convert launch.
// R16's nontemporal C-store reverted (null on FETCH, +WRITE, -3% time).

typedef __attribute__((ext_vector_type(8))) short short8;
typedef __attribute__((ext_vector_type(4))) float f32x4;

#define M_DIM 8192
#define N_DIM 4096
#define K_DIM 2048
#define BM 128
#define BN 128
#define BK 64
#define NT (K_DIM / BK)  // 32

#define AS1 __attribute__((address_space(1)))
#define AS3 __attribute__((address_space(3)))

// ---------------- fused f32 -> bf16 (RNE) convert: x then W ----------------
__global__ void cvt_both_k(const float* __restrict__ x, const float* __restrict__ wgt,
                           ushort* __restrict__ xb, ushort* __restrict__ wb) {
    const int n8x = (M_DIM * K_DIM) / 8;          // 2M chunks for x
    int i = blockIdx.x * blockDim.x + threadIdx.x;
    const float* src;
    ushort* dst;
    int idx;
    if (i < n8x) { src = x; dst = xb; idx = i; }
    else         { src = wgt; dst = wb; idx = i - n8x; }
    const float4* p = (const float4*)src + 2 * (size_t)idx;
    float4 a = p[0], b = p[1];
    float v[8] = {a.x, a.y, a.z, a.w, b.x, b.y, b.z, b.w};
    ushort rr[8];
#pragma unroll
    for (int j = 0; j < 8; ++j) {
        unsigned u = __float_as_uint(v[j]);
        rr[j] = (ushort)((u + 0x7fffu + ((u >> 16) & 1u)) >> 16);  // RNE
    }
    uint4 o;
    o.x = (unsigned)rr[0] | ((unsigned)rr[1] << 16);
    o.y = (unsigned)rr[2] | ((unsigned)rr[3] << 16);
    o.z = (unsigned)rr[4] | ((unsigned)rr[5] << 16);
    o.w = (unsigned)rr[6] | ((unsigned)rr[7] << 16);
    ((uint4*)dst)[idx] = o;
}

// LDS (ushort offsets): A [0,8192): 128 rows x 64 sh (128B rows, kk0|kk1
// halves in-row); B [8192,16384); stats floats at 16384 (2KB).
// 16B-slot stored at (row,s) holds k-chunk s ^ (row&7); read uses slot
// (kk*4+h) ^ (r&7)  [0-conflict, proven R2/R5-R10/R13/R15]. Source pre-swizzled.

__global__ __launch_bounds__(256, 4) void gemm_swish_gn(
    const ushort* __restrict__ xb, const ushort* __restrict__ wb,
    const float* __restrict__ bias_lin, const float* __restrict__ bias_extra,
    const float* __restrict__ gn_w, const float* __restrict__ gn_b,
    float* __restrict__ out)
{
    extern __shared__ __align__(16) ushort lds[];

    const int t = threadIdx.x;
    const int w = t >> 6;        // 4 waves: 2M x 2N
    const int l = t & 63;
    const int wm = w >> 1;       // 0..1
    const int wn = w & 1;        // 0..1
    const int h = l >> 4;        // 0..3
    const int r = l & 15;        // 0..15

    // XCD swizzle: 2048 blocks; 8 XCDs as 4x2 grid of 16x16-tile patches.
    const int bid = blockIdx.x;
    const int xcd = bid & 7;
    const int pp = bid >> 3;                      // 0..255
    const int brow = (xcd & 3) * 16 + (pp & 15);  // 0..63
    const int bcol = (xcd >> 2) * 16 + (pp >> 4); // 0..31  (= GN group)

    // ---- staging: thread t -> row s=t>>3 (32 rows/round), slot t&7;
    // source col pre-swizzled: slot ^= (s&7).
    const int s = t >> 3;
    const int scol = (((t & 7) ^ (s & 7)) << 3);  // ushorts
    const ushort* pA = xb + (size_t)(brow * BM + s) * K_DIM + scol;
    const ushort* pB = wb + (size_t)(bcol * BN + s) * K_DIM + scol;
    const int dst = t * 8;

#define STG_A(ROFF) __builtin_amdgcn_global_load_lds(                          \
        (const AS1 void*)(pA + (size_t)(ROFF) * K_DIM),                        \
        (AS3 void*)&lds[(ROFF) * 64 + dst], 16, 0, 0)
#define STG_B(ROFF) __builtin_amdgcn_global_load_lds(                          \
        (const AS1 void*)(pB + (size_t)(ROFF) * K_DIM),                        \
        (AS3 void*)&lds[8192 + (ROFF) * 64 + dst], 16, 0, 0)

    // fragment read offsets (ushorts): row*64 + ((kk*32 + h*8) ^ (r&7)*8)
    const int xr8 = (r & 7) << 3;
    const int aOff0 = (wm * 64 + r) * 64 + ((h << 3) ^ xr8);   // + m*1024
    const int aOff1 = aOff0 ^ 32;                              // kk1
    const int bOff0 = 8192 + (wn * 64 + r) * 64 + ((h << 3) ^ xr8);
    const int bOff1 = bOff0 ^ 32;

    f32x4 acc[4][4];
#pragma unroll
    for (int m = 0; m < 4; ++m)
#pragma unroll
        for (int n = 0; n < 4; ++n)
            acc[m][n] = f32x4{0.f, 0.f, 0.f, 0.f};

    short8 aF[4][2], bF[4][2];

#pragma unroll 1
    for (int kt = 0; kt < NT; ++kt) {
        // ---- stage tile kt (8 x gload_lds w16) ----
        STG_A(0); STG_A(32); STG_A(64); STG_A(96);
        STG_B(0); STG_B(32); STG_B(64); STG_B(96);
        pA += BK; pB += BK;
        __syncthreads();   // compiler drains vmcnt -> LDS writes visible

        // ---- read fragments + 32 MFMA ----
#pragma unroll
        for (int m = 0; m < 4; ++m) {
            aF[m][0] = *(const short8*)&lds[aOff0 + m * 1024];
            aF[m][1] = *(const short8*)&lds[aOff1 + m * 1024];
        }
#pragma unroll
        for (int n = 0; n < 4; ++n) {
            bF[n][0] = *(const short8*)&lds[bOff0 + n * 1024];
            bF[n][1] = *(const short8*)&lds[bOff1 + n * 1024];
        }
#pragma unroll
        for (int kk = 0; kk < 2; ++kk)
#pragma unroll
            for (int m = 0; m < 4; ++m)
#pragma unroll
                for (int n = 0; n < 4; ++n)
                    acc[m][n] = __builtin_amdgcn_mfma_f32_16x16x32_bf16(
                        aF[m][kk], bF[n][kk], acc[m][n], 0, 0, 0);

        __syncthreads();   // reads done before next stage overwrites
    }

    // ---- epilogue: bias + swish + extra bias; GroupNorm (group == block cols)
    // acc[m][n][j]: row = wm*64 + m*16 + h*4 + j, col = wn*64 + n*16 + r
    const int colbase = bcol * BN + wn * 64;
    float bl[4], be[4], gwv[4], gbv[4];
#pragma unroll
    for (int n = 0; n < 4; ++n) {
        int col = colbase + n * 16 + r;
        bl[n] = bias_lin[col];
        be[n] = bias_extra[col];
        gwv[n] = gn_w[col];
        gbv[n] = gn_b[col];
    }

    float s1[4][4], s2[4][4];
#pragma unroll
    for (int m = 0; m < 4; ++m)
#pragma unroll
        for (int j = 0; j < 4; ++j) { s1[m][j] = 0.f; s2[m][j] = 0.f; }

#pragma unroll
    for (int m = 0; m < 4; ++m)
#pragma unroll
        for (int n = 0; n < 4; ++n)
#pragma unroll
            for (int j = 0; j < 4; ++j) {
                float z = acc[m][n][j] + bl[n];
                float sw = z / (1.f + __expf(-z)) + be[n];
                acc[m][n][j] = sw;
                s1[m][j] += sw;
                s2[m][j] += sw * sw;
            }

#pragma unroll
    for (int mask = 1; mask < 16; mask <<= 1) {
#pragma unroll
        for (int m = 0; m < 4; ++m)
#pragma unroll
            for (int j = 0; j < 4; ++j) {
                s1[m][j] += __shfl_xor(s1[m][j], mask, 16);
                s2[m][j] += __shfl_xor(s2[m][j], mask, 16);
            }
    }

    float* sred = (float*)&lds[16384];  // [2 stat][2 wn][128 rows]
    if (r == 0) {
#pragma unroll
        for (int m = 0; m < 4; ++m)
#pragma unroll
            for (int j = 0; j < 4; ++j) {
                int row = wm * 64 + m * 16 + h * 4 + j;
                sred[(0 * 2 + wn) * 128 + row] = s1[m][j];
                sred[(1 * 2 + wn) * 128 + row] = s2[m][j];
            }
    }
    __syncthreads();

    const size_t orow0 = (size_t)brow * BM;
#pragma unroll
    for (int m = 0; m < 4; ++m)
#pragma unroll
        for (int j = 0; j < 4; ++j) {
            int row = wm * 64 + m * 16 + h * 4 + j;
            float mu = (sred[0 * 128 + row] + sred[1 * 128 + row]) * (1.f / 128.f);
            float ex2 = (sred[2 * 128 + row] + sred[3 * 128 + row]) * (1.f / 128.f);
            float var = ex2 - mu * mu;
            float rs = rsqrtf(var + 1e-5f);
            float* orow = out + (orow0 + row) * N_DIM;
#pragma unroll
            for (int n = 0; n < 4; ++n) {
                int col = colbase + n * 16 + r;
                orow[col] = (acc[m][n][j] - mu) * rs * gwv[n] + gbv[n];
            }
        }
}

extern "C" void kernel_launch(void* const* d_in, const int* in_sizes, int n_in,
                              void* d_out, int out_size, void* d_ws, size_t ws_size,
                              hipStream_t stream) {
    const float* x        = (const float*)d_in[0];
    const float* weight   = (const float*)d_in[1];
    const float* bias_lin = (const float*)d_in[2];
    const float* bias_ex  = (const float*)d_in[3];
    const float* gn_w     = (const float*)d_in[4];
    const float* gn_b     = (const float*)d_in[5];
    float* out = (float*)d_out;

    ushort* xb = (ushort*)d_ws;                     // 32 MiB bf16
    ushort* wb = xb + (size_t)M_DIM * K_DIM;        // 16 MiB bf16

    {
        int n8 = (M_DIM * K_DIM + N_DIM * K_DIM) / 8;   // 3M chunks
        cvt_both_k<<<n8 / 256, 256, 0, stream>>>(x, weight, xb, wb);
    }

    // dynamic LDS: 16KB A + 16KB B + 2KB stats = 34816 B  (4 blocks/CU)
    const size_t ldsB = 16384 * sizeof(ushort) + 512 * sizeof(float);
    dim3 grid((M_DIM / BM) * (N_DIM / BN));  // 2048 blocks
    gemm_swish_gn<<<grid, 256, ldsB, stream>>>(xb, wb, bias_lin, bias_ex, gn_w, gn_b, out);
}

// Round 18
// 181.552 us; speedup vs baseline: 1.0680x; 1.0680x over previous
//
#include <hip/hip_runtime.h>

// Fused: z = x @ W^T + b_lin; y = swish(z) + b_ex; GroupNorm(32 groups) * gn_w + gn_b
// x: [8192, 2048] f32, W: [4096, 2048] f32, out: [8192, 4096] f32
// Round 18 (FINAL): best-bench-total config = R10's launch_bounds(256,3)
// (182.0us total vs 193.5+-0.3 for (256,4) triple) + fused single-launch cvt.
// Kernel body = proven best: 128x128 tile, BK=64, 16x16x32 MFMA, single 34KB
// LDS buffer, plain 2-barrier loop, 0-conflict swizzled layout, XCD patches,
// GN fused in epilogue (N-tile == GN group).

typedef __attribute__((ext_vector_type(8))) short short8;
typedef __attribute__((ext_vector_type(4))) float f32x4;

#define M_DIM 8192
#define N_DIM 4096
#define K_DIM 2048
#define BM 128
#define BN 128
#define BK 64
#define NT (K_DIM / BK)  // 32

#define AS1 __attribute__((address_space(1)))
#define AS3 __attribute__((address_space(3)))

// ---------------- fused f32 -> bf16 (RNE) convert: x then W ----------------
__global__ void cvt_both_k(const float* __restrict__ x, const float* __restrict__ wgt,
                           ushort* __restrict__ xb, ushort* __restrict__ wb) {
    const int n8x = (M_DIM * K_DIM) / 8;          // 2M chunks for x
    int i = blockIdx.x * blockDim.x + threadIdx.x;
    const float* src;
    ushort* dst;
    int idx;
    if (i < n8x) { src = x; dst = xb; idx = i; }
    else         { src = wgt; dst = wb; idx = i - n8x; }
    const float4* p = (const float4*)src + 2 * (size_t)idx;
    float4 a = p[0], b = p[1];
    float v[8] = {a.x, a.y, a.z, a.w, b.x, b.y, b.z, b.w};
    ushort rr[8];
#pragma unroll
    for (int j = 0; j < 8; ++j) {
        unsigned u = __float_as_uint(v[j]);
        rr[j] = (ushort)((u + 0x7fffu + ((u >> 16) & 1u)) >> 16);  // RNE
    }
    uint4 o;
    o.x = (unsigned)rr[0] | ((unsigned)rr[1] << 16);
    o.y = (unsigned)rr[2] | ((unsigned)rr[3] << 16);
    o.z = (unsigned)rr[4] | ((unsigned)rr[5] << 16);
    o.w = (unsigned)rr[6] | ((unsigned)rr[7] << 16);
    ((uint4*)dst)[idx] = o;
}

// LDS (ushort offsets): A [0,8192): 128 rows x 64 sh (128B rows, kk0|kk1
// halves in-row); B [8192,16384); stats floats at 16384 (2KB).
// 16B-slot stored at (row,s) holds k-chunk s ^ (row&7); read uses slot
// (kk*4+h) ^ (r&7)  [0-conflict, proven R2/R5-R10/R13/R15/R17].
// Source col pre-swizzled by the same involution (rule #21).

__global__ __launch_bounds__(256, 3) void gemm_swish_gn(
    const ushort* __restrict__ xb, const ushort* __restrict__ wb,
    const float* __restrict__ bias_lin, const float* __restrict__ bias_extra,
    const float* __restrict__ gn_w, const float* __restrict__ gn_b,
    float* __restrict__ out)
{
    extern __shared__ __align__(16) ushort lds[];

    const int t = threadIdx.x;
    const int w = t >> 6;        // 4 waves: 2M x 2N
    const int l = t & 63;
    const int wm = w >> 1;       // 0..1
    const int wn = w & 1;        // 0..1
    const int h = l >> 4;        // 0..3
    const int r = l & 15;        // 0..15

    // XCD swizzle: 2048 blocks; 8 XCDs as 4x2 grid of 16x16-tile patches.
    const int bid = blockIdx.x;
    const int xcd = bid & 7;
    const int pp = bid >> 3;                      // 0..255
    const int brow = (xcd & 3) * 16 + (pp & 15);  // 0..63
    const int bcol = (xcd >> 2) * 16 + (pp >> 4); // 0..31  (= GN group)

    // ---- staging: thread t -> row s=t>>3 (32 rows/round), slot t&7;
    // source col pre-swizzled: slot ^= (s&7).
    const int s = t >> 3;
    const int scol = (((t & 7) ^ (s & 7)) << 3);  // ushorts
    const ushort* pA = xb + (size_t)(brow * BM + s) * K_DIM + scol;
    const ushort* pB = wb + (size_t)(bcol * BN + s) * K_DIM + scol;
    const int dst = t * 8;

#define STG_A(ROFF) __builtin_amdgcn_global_load_lds(                          \
        (const AS1 void*)(pA + (size_t)(ROFF) * K_DIM),                        \
        (AS3 void*)&lds[(ROFF) * 64 + dst], 16, 0, 0)
#define STG_B(ROFF) __builtin_amdgcn_global_load_lds(                          \
        (const AS1 void*)(pB + (size_t)(ROFF) * K_DIM),                        \
        (AS3 void*)&lds[8192 + (ROFF) * 64 + dst], 16, 0, 0)

    // fragment read offsets (ushorts): row*64 + ((kk*32 + h*8) ^ (r&7)*8)
    const int xr8 = (r & 7) << 3;
    const int aOff0 = (wm * 64 + r) * 64 + ((h << 3) ^ xr8);   // + m*1024
    const int aOff1 = aOff0 ^ 32;                              // kk1
    const int bOff0 = 8192 + (wn * 64 + r) * 64 + ((h << 3) ^ xr8);
    const int bOff1 = bOff0 ^ 32;

    f32x4 acc[4][4];
#pragma unroll
    for (int m = 0; m < 4; ++m)
#pragma unroll
        for (int n = 0; n < 4; ++n)
            acc[m][n] = f32x4{0.f, 0.f, 0.f, 0.f};

    short8 aF[4][2], bF[4][2];

#pragma unroll 1
    for (int kt = 0; kt < NT; ++kt) {
        // ---- stage tile kt (8 x gload_lds w16) ----
        STG_A(0); STG_A(32); STG_A(64); STG_A(96);
        STG_B(0); STG_B(32); STG_B(64); STG_B(96);
        pA += BK; pB += BK;
        __syncthreads();   // compiler drains vmcnt -> LDS writes visible

        // ---- read fragments + 32 MFMA ----
#pragma unroll
        for (int m = 0; m < 4; ++m) {
            aF[m][0] = *(const short8*)&lds[aOff0 + m * 1024];
            aF[m][1] = *(const short8*)&lds[aOff1 + m * 1024];
        }
#pragma unroll
        for (int n = 0; n < 4; ++n) {
            bF[n][0] = *(const short8*)&lds[bOff0 + n * 1024];
            bF[n][1] = *(const short8*)&lds[bOff1 + n * 1024];
        }
#pragma unroll
        for (int kk = 0; kk < 2; ++kk)
#pragma unroll
            for (int m = 0; m < 4; ++m)
#pragma unroll
                for (int n = 0; n < 4; ++n)
                    acc[m][n] = __builtin_amdgcn_mfma_f32_16x16x32_bf16(
                        aF[m][kk], bF[n][kk], acc[m][n], 0, 0, 0);

        __syncthreads();   // reads done before next stage overwrites
    }

    // ---- epilogue: bias + swish + extra bias; GroupNorm (group == block cols)
    // acc[m][n][j]: row = wm*64 + m*16 + h*4 + j, col = wn*64 + n*16 + r
    const int colbase = bcol * BN + wn * 64;
    float bl[4], be[4], gwv[4], gbv[4];
#pragma unroll
    for (int n = 0; n < 4; ++n) {
        int col = colbase + n * 16 + r;
        bl[n] = bias_lin[col];
        be[n] = bias_extra[col];
        gwv[n] = gn_w[col];
        gbv[n] = gn_b[col];
    }

    float s1[4][4], s2[4][4];
#pragma unroll
    for (int m = 0; m < 4; ++m)
#pragma unroll
        for (int j = 0; j < 4; ++j) { s1[m][j] = 0.f; s2[m][j] = 0.f; }

#pragma unroll
    for (int m = 0; m < 4; ++m)
#pragma unroll
        for (int n = 0; n < 4; ++n)
#pragma unroll
            for (int j = 0; j < 4; ++j) {
                float z = acc[m][n][j] + bl[n];
                float sw = z / (1.f + __expf(-z)) + be[n];
                acc[m][n][j] = sw;
                s1[m][j] += sw;
                s2[m][j] += sw * sw;
            }

#pragma unroll
    for (int mask = 1; mask < 16; mask <<= 1) {
#pragma unroll
        for (int m = 0; m < 4; ++m)
#pragma unroll
            for (int j = 0; j < 4; ++j) {
                s1[m][j] += __shfl_xor(s1[m][j], mask, 16);
                s2[m][j] += __shfl_xor(s2[m][j], mask, 16);
            }
    }

    float* sred = (float*)&lds[16384];  // [2 stat][2 wn][128 rows]
    if (r == 0) {
#pragma unroll
        for (int m = 0; m < 4; ++m)
#pragma unroll
            for (int j = 0; j < 4; ++j) {
                int row = wm * 64 + m * 16 + h * 4 + j;
                sred[(0 * 2 + wn) * 128 + row] = s1[m][j];
                sred[(1 * 2 + wn) * 128 + row] = s2[m][j];
            }
    }
    __syncthreads();

    const size_t orow0 = (size_t)brow * BM;
#pragma unroll
    for (int m = 0; m < 4; ++m)
#pragma unroll
        for (int j = 0; j < 4; ++j) {
            int row = wm * 64 + m * 16 + h * 4 + j;
            float mu = (sred[0 * 128 + row] + sred[1 * 128 + row]) * (1.f / 128.f);
            float ex2 = (sred[2 * 128 + row] + sred[3 * 128 + row]) * (1.f / 128.f);
            float var = ex2 - mu * mu;
            float rs = rsqrtf(var + 1e-5f);
            float* orow = out + (orow0 + row) * N_DIM;
#pragma unroll
            for (int n = 0; n < 4; ++n) {
                int col = colbase + n * 16 + r;
                orow[col] = (acc[m][n][j] - mu) * rs * gwv[n] + gbv[n];
            }
        }
}

extern "C" void kernel_launch(void* const* d_in, const int* in_sizes, int n_in,
                              void* d_out, int out_size, void* d_ws, size_t ws_size,
                              hipStream_t stream) {
    const float* x        = (const float*)d_in[0];
    const float* weight   = (const float*)d_in[1];
    const float* bias_lin = (const float*)d_in[2];
    const float* bias_ex  = (const float*)d_in[3];
    const float* gn_w     = (const float*)d_in[4];
    const float* gn_b     = (const float*)d_in[5];
    float* out = (float*)d_out;

    ushort* xb = (ushort*)d_ws;                     // 32 MiB bf16
    ushort* wb = xb + (size_t)M_DIM * K_DIM;        // 16 MiB bf16

    {
        int n8 = (M_DIM * K_DIM + N_DIM * K_DIM) / 8;   // 3M chunks
        cvt_both_k<<<n8 / 256, 256, 0, stream>>>(x, weight, xb, wb);
    }

    // dynamic LDS: 16KB A + 16KB B + 2KB stats = 34816 B
    const size_t ldsB = 16384 * sizeof(ushort) + 512 * sizeof(float);
    dim3 grid((M_DIM / BM) * (N_DIM / BN));  // 2048 blocks
    gemm_swish_gn<<<grid, 256, ldsB, stream>>>(xb, wb, bias_lin, bias_ex, gn_w, gn_b, out);
}

// Round 19
// 181.310 us; speedup vs baseline: 1.0694x; 1.0013x over previous
//
#include <hip/hip_runtime.h>

// Fused: z = x @ W^T + b_lin; y = swish(z) + b_ex; GroupNorm(32 groups) * gn_w + gn_b
// x: [8192, 2048] f32, W: [4096, 2048] f32, out: [8192, 4096] f32
// FINAL (R18 confirmed best, 181.6us total): 128x128 tile, BK=64, 16x16x32
// MFMA, single 34KB LDS buffer, plain 2-barrier loop, 0-conflict swizzled
// layout, XCD patches, launch_bounds(256,3), GN fused in epilogue
// (N-tile == GN group), single fused f32->bf16 convert launch.
//
// Session ledger: (256,3)+(256,4) swept -> 3 best in timed graph; deep-pipeline
// family (counted vmcnt / phases / asm ds_read / setprio) 0-for-8 at this
// structure; kernel is LDS-pipe-dominated (MFMA/LDS cyc = 55%, achieved LDS
// eff ~68% -> MfmaUtil 37% plateau, matches m134 b128 ceiling).

typedef __attribute__((ext_vector_type(8))) short short8;
typedef __attribute__((ext_vector_type(4))) float f32x4;

#define M_DIM 8192
#define N_DIM 4096
#define K_DIM 2048
#define BM 128
#define BN 128
#define BK 64
#define NT (K_DIM / BK)  // 32

#define AS1 __attribute__((address_space(1)))
#define AS3 __attribute__((address_space(3)))

// ---------------- fused f32 -> bf16 (RNE) convert: x then W ----------------
__global__ void cvt_both_k(const float* __restrict__ x, const float* __restrict__ wgt,
                           ushort* __restrict__ xb, ushort* __restrict__ wb) {
    const int n8x = (M_DIM * K_DIM) / 8;          // 2M chunks for x
    int i = blockIdx.x * blockDim.x + threadIdx.x;
    const float* src;
    ushort* dst;
    int idx;
    if (i < n8x) { src = x; dst = xb; idx = i; }
    else         { src = wgt; dst = wb; idx = i - n8x; }
    const float4* p = (const float4*)src + 2 * (size_t)idx;
    float4 a = p[0], b = p[1];
    float v[8] = {a.x, a.y, a.z, a.w, b.x, b.y, b.z, b.w};
    ushort rr[8];
#pragma unroll
    for (int j = 0; j < 8; ++j) {
        unsigned u = __float_as_uint(v[j]);
        rr[j] = (ushort)((u + 0x7fffu + ((u >> 16) & 1u)) >> 16);  // RNE
    }
    uint4 o;
    o.x = (unsigned)rr[0] | ((unsigned)rr[1] << 16);
    o.y = (unsigned)rr[2] | ((unsigned)rr[3] << 16);
    o.z = (unsigned)rr[4] | ((unsigned)rr[5] << 16);
    o.w = (unsigned)rr[6] | ((unsigned)rr[7] << 16);
    ((uint4*)dst)[idx] = o;
}

// LDS (ushort offsets): A [0,8192): 128 rows x 64 sh (128B rows, kk0|kk1
// halves in-row); B [8192,16384); stats floats at 16384 (2KB).
// 16B-slot stored at (row,s) holds k-chunk s ^ (row&7); read uses slot
// (kk*4+h) ^ (r&7)  [0-conflict, proven across R2/R5-R10/R13/R15/R17/R18].
// Source col pre-swizzled by the same involution (rule #21).

__global__ __launch_bounds__(256, 3) void gemm_swish_gn(
    const ushort* __restrict__ xb, const ushort* __restrict__ wb,
    const float* __restrict__ bias_lin, const float* __restrict__ bias_extra,
    const float* __restrict__ gn_w, const float* __restrict__ gn_b,
    float* __restrict__ out)
{
    extern __shared__ __align__(16) ushort lds[];

    const int t = threadIdx.x;
    const int w = t >> 6;        // 4 waves: 2M x 2N
    const int l = t & 63;
    const int wm = w >> 1;       // 0..1
    const int wn = w & 1;        // 0..1
    const int h = l >> 4;        // 0..3
    const int r = l & 15;        // 0..15

    // XCD swizzle: 2048 blocks; 8 XCDs as 4x2 grid of 16x16-tile patches.
    const int bid = blockIdx.x;
    const int xcd = bid & 7;
    const int pp = bid >> 3;                      // 0..255
    const int brow = (xcd & 3) * 16 + (pp & 15);  // 0..63
    const int bcol = (xcd >> 2) * 16 + (pp >> 4); // 0..31  (= GN group)

    // ---- staging: thread t -> row s=t>>3 (32 rows/round), slot t&7;
    // source col pre-swizzled: slot ^= (s&7).
    const int s = t >> 3;
    const int scol = (((t & 7) ^ (s & 7)) << 3);  // ushorts
    const ushort* pA = xb + (size_t)(brow * BM + s) * K_DIM + scol;
    const ushort* pB = wb + (size_t)(bcol * BN + s) * K_DIM + scol;
    const int dst = t * 8;

#define STG_A(ROFF) __builtin_amdgcn_global_load_lds(                          \
        (const AS1 void*)(pA + (size_t)(ROFF) * K_DIM),                        \
        (AS3 void*)&lds[(ROFF) * 64 + dst], 16, 0, 0)
#define STG_B(ROFF) __builtin_amdgcn_global_load_lds(                          \
        (const AS1 void*)(pB + (size_t)(ROFF) * K_DIM),                        \
        (AS3 void*)&lds[8192 + (ROFF) * 64 + dst], 16, 0, 0)

    // fragment read offsets (ushorts): row*64 + ((kk*32 + h*8) ^ (r&7)*8)
    const int xr8 = (r & 7) << 3;
    const int aOff0 = (wm * 64 + r) * 64 + ((h << 3) ^ xr8);   // + m*1024
    const int aOff1 = aOff0 ^ 32;                              // kk1
    const int bOff0 = 8192 + (wn * 64 + r) * 64 + ((h << 3) ^ xr8);
    const int bOff1 = bOff0 ^ 32;

    f32x4 acc[4][4];
#pragma unroll
    for (int m = 0; m < 4; ++m)
#pragma unroll
        for (int n = 0; n < 4; ++n)
            acc[m][n] = f32x4{0.f, 0.f, 0.f, 0.f};

    short8 aF[4][2], bF[4][2];

#pragma unroll 1
    for (int kt = 0; kt < NT; ++kt) {
        // ---- stage tile kt (8 x gload_lds w16) ----
        STG_A(0); STG_A(32); STG_A(64); STG_A(96);
        STG_B(0); STG_B(32); STG_B(64); STG_B(96);
        pA += BK; pB += BK;
        __syncthreads();   // compiler drains vmcnt -> LDS writes visible

        // ---- read fragments + 32 MFMA ----
#pragma unroll
        for (int m = 0; m < 4; ++m) {
            aF[m][0] = *(const short8*)&lds[aOff0 + m * 1024];
            aF[m][1] = *(const short8*)&lds[aOff1 + m * 1024];
        }
#pragma unroll
        for (int n = 0; n < 4; ++n) {
            bF[n][0] = *(const short8*)&lds[bOff0 + n * 1024];
            bF[n][1] = *(const short8*)&lds[bOff1 + n * 1024];
        }
#pragma unroll
        for (int kk = 0; kk < 2; ++kk)
#pragma unroll
            for (int m = 0; m < 4; ++m)
#pragma unroll
                for (int n = 0; n < 4; ++n)
                    acc[m][n] = __builtin_amdgcn_mfma_f32_16x16x32_bf16(
                        aF[m][kk], bF[n][kk], acc[m][n], 0, 0, 0);

        __syncthreads();   // reads done before next stage overwrites
    }

    // ---- epilogue: bias + swish + extra bias; GroupNorm (group == block cols)
    // acc[m][n][j]: row = wm*64 + m*16 + h*4 + j, col = wn*64 + n*16 + r
    const int colbase = bcol * BN + wn * 64;
    float bl[4], be[4], gwv[4], gbv[4];
#pragma unroll
    for (int n = 0; n < 4; ++n) {
        int col = colbase + n * 16 + r;
        bl[n] = bias_lin[col];
        be[n] = bias_extra[col];
        gwv[n] = gn_w[col];
        gbv[n] = gn_b[col];
    }

    float s1[4][4], s2[4][4];
#pragma unroll
    for (int m = 0; m < 4; ++m)
#pragma unroll
        for (int j = 0; j < 4; ++j) { s1[m][j] = 0.f; s2[m][j] = 0.f; }

#pragma unroll
    for (int m = 0; m < 4; ++m)
#pragma unroll
        for (int n = 0; n < 4; ++n)
#pragma unroll
            for (int j = 0; j < 4; ++j) {
                float z = acc[m][n][j] + bl[n];
                float sw = z / (1.f + __expf(-z)) + be[n];
                acc[m][n][j] = sw;
                s1[m][j] += sw;
                s2[m][j] += sw * sw;
            }

#pragma unroll
    for (int mask = 1; mask < 16; mask <<= 1) {
#pragma unroll
        for (int m = 0; m < 4; ++m)
#pragma unroll
            for (int j = 0; j < 4; ++j) {
                s1[m][j] += __shfl_xor(s1[m][j], mask, 16);
                s2[m][j] += __shfl_xor(s2[m][j], mask, 16);
            }
    }

    float* sred = (float*)&lds[16384];  // [2 stat][2 wn][128 rows]
    if (r == 0) {
#pragma unroll
        for (int m = 0; m < 4; ++m)
#pragma unroll
            for (int j = 0; j < 4; ++j) {
                int row = wm * 64 + m * 16 + h * 4 + j;
                sred[(0 * 2 + wn) * 128 + row] = s1[m][j];
                sred[(1 * 2 + wn) * 128 + row] = s2[m][j];
            }
    }
    __syncthreads();

    const size_t orow0 = (size_t)brow * BM;
#pragma unroll
    for (int m = 0; m < 4; ++m)
#pragma unroll
        for (int j = 0; j < 4; ++j) {
            int row = wm * 64 + m * 16 + h * 4 + j;
            float mu = (sred[0 * 128 + row] + sred[1 * 128 + row]) * (1.f / 128.f);
            float ex2 = (sred[2 * 128 + row] + sred[3 * 128 + row]) * (1.f / 128.f);
            float var = ex2 - mu * mu;
            float rs = rsqrtf(var + 1e-5f);
            float* orow = out + (orow0 + row) * N_DIM;
#pragma unroll
            for (int n = 0; n < 4; ++n) {
                int col = colbase + n * 16 + r;
                orow[col] = (acc[m][n][j] - mu) * rs * gwv[n] + gbv[n];
            }
        }
}

extern "C" void kernel_launch(void* const* d_in, const int* in_sizes, int n_in,
                              void* d_out, int out_size, void* d_ws, size_t ws_size,
                              hipStream_t stream) {
    const float* x        = (const float*)d_in[0];
    const float* weight   = (const float*)d_in[1];
    const float* bias_lin = (const float*)d_in[2];
    const float* bias_ex  = (const float*)d_in[3];
    const float* gn_w     = (const float*)d_in[4];
    const float* gn_b     = (const float*)d_in[5];
    float* out = (float*)d_out;

    ushort* xb = (ushort*)d_ws;                     // 32 MiB bf16
    ushort* wb = xb + (size_t)M_DIM * K_DIM;        // 16 MiB bf16

    {
        int n8 = (M_DIM * K_DIM + N_DIM * K_DIM) / 8;   // 3M chunks
        cvt_both_k<<<n8 / 256, 256, 0, stream>>>(x, weight, xb, wb);
    }

    // dynamic LDS: 16KB A + 16KB B + 2KB stats = 34816 B
    const size_t ldsB = 16384 * sizeof(ushort) + 512 * sizeof(float);
    dim3 grid((M_DIM / BM) * (N_DIM / BN));  // 2048 blocks
    gemm_swish_gn<<<grid, 256, ldsB, stream>>>(xb, wb, bias_lin, bias_ex, gn_w, gn_b, out);
}